// Round 6
// baseline (140.990 us; speedup 1.0000x reference)
//
#include <hip/hip_runtime.h>
#include <hip/hip_bf16.h>
#include <hip/hip_cooperative_groups.h>

namespace cg = cooperative_groups;

#define B_   16
#define T_   8192
#define H_   256
#define C_   11
#define KCH  256            // chunks per batch
#define LCH  32             // steps per chunk (T_/KCH)
#define NC   (B_*KCH)       // total chunks

typedef __attribute__((ext_vector_type(8))) short short8;
typedef __attribute__((ext_vector_type(4))) float f32x4;

// ---------------------------------------------------------------------------
// bf16 emission row load/unpack helpers
// ---------------------------------------------------------------------------
__device__ __forceinline__ void loadRow(const unsigned short* __restrict__ p,
                                        uint4& qa, uint2& qb) {
    qa = *(const uint4*)p;
    qb = *(const uint2*)(p + 8);
}
__device__ __forceinline__ void unpackRow(uint4 qa, uint2 qb, float* emv) {
    emv[0]  = __uint_as_float(qa.x << 16);
    emv[1]  = __uint_as_float(qa.x & 0xffff0000u);
    emv[2]  = __uint_as_float(qa.y << 16);
    emv[3]  = __uint_as_float(qa.y & 0xffff0000u);
    emv[4]  = __uint_as_float(qa.z << 16);
    emv[5]  = __uint_as_float(qa.z & 0xffff0000u);
    emv[6]  = __uint_as_float(qa.w << 16);
    emv[7]  = __uint_as_float(qa.w & 0xffff0000u);
    emv[8]  = __uint_as_float(qb.x << 16);
    emv[9]  = __uint_as_float(qb.x & 0xffff0000u);
    emv[10] = __uint_as_float(qb.y << 16);
}

// ---------------------------------------------------------------------------
// ONE cooperative kernel, 256 blocks x 512 threads, 135 KB LDS (1 block/CU,
// exactly co-resident). Phases split by grid.sync():
//  0: stage weights in LDS; MFMA encoder+emissions+numerator (2 half-blocks
//     = two of the old 256-thread k_em blocks)
//  1: 4096 chunk transfer matrices (4 waves x 4 chunks per block)
//  2: blocks 0..15: per-batch LDS tree combine -> dens[b]
//  3: block 0: final scalar
// ---------------------------------------------------------------------------
__global__ __launch_bounds__(512, 2) void k_all(
    const float* __restrict__ seq, const float* __restrict__ Wenc,
    const float* __restrict__ benc, const float* __restrict__ Wemit,
    const float* __restrict__ bemit, const float* __restrict__ startt,
    const float* __restrict__ trans, const float* __restrict__ endt,
    const int* __restrict__ lengths, const int* __restrict__ labels,
    unsigned short* __restrict__ expem, float* __restrict__ G0,
    float* __restrict__ numpart, float* __restrict__ dens,
    float* __restrict__ out)
{
    cg::grid_group grid = cg::this_grid();

    __shared__ __align__(16) float ldsf[KCH * 132];   // 135168 B, aliased
    float* ldsWpack = ldsf;                // [256][8]: w0..w3, benc, pad
    float* ldsWemit = ldsf + 2048;         // [256][16]: Wemit padded
    float* red      = ldsf + 2048 + 4096;  // [8]

    int tid  = threadIdx.x;
    int bk   = blockIdx.x;
    int wid8 = tid >> 6;
    int lane = tid & 63;

    // ============================ phase 0 ==================================
    {
        // stage weights (coalesced enough; L2-resident after first blocks)
        for (int idx = tid; idx < 2048; idx += 512) {
            int h = idx >> 3, s = idx & 7;
            float v = 0.f;
            if (s < 4) v = Wenc[s * H_ + h];
            else if (s == 4) v = benc[h];
            ldsWpack[idx] = v;
        }
        for (int idx = tid; idx < 4096; idx += 512) {
            int h = idx >> 4, c = idx & 15;
            ldsWemit[idx] = (c < C_) ? Wemit[h * C_ + c] : 0.f;
        }
        __syncthreads();

        int hb = tid >> 8;                    // half-block 0/1
        int g = lane >> 4, li = lane & 15;
        int emb = (bk << 1) | hb;             // 0..511 (old k_em blockIdx)
        int wloc = wid8 & 3;                  // wave within half-block
        int b0 = emb >> 5;
        int tb0 = (emb & 31) * 256 + wloc * 64;
        size_t grow0 = (size_t)b0 * T_ + tb0;

        float4 xs[4];
#pragma unroll
        for (int tt = 0; tt < 4; tt++)
            xs[tt] = *(const float4*)(seq + (grow0 + tt * 16 + li) * 4);

        f32x4 acc[4];
#pragma unroll
        for (int tt = 0; tt < 4; tt++) acc[tt] = (f32x4){0.f, 0.f, 0.f, 0.f};

#pragma unroll 1
        for (int kb = 0; kb < 8; kb++) {
            float We[8][5], wm[8];
#pragma unroll
            for (int e = 0; e < 8; e++) {
                int h = 32 * kb + 4 * g + (e & 3) + 16 * (e >> 2);
                float4 w4 = *(const float4*)&ldsWpack[h * 8];
                We[e][0] = w4.x; We[e][1] = w4.y; We[e][2] = w4.z; We[e][3] = w4.w;
                We[e][4] = ldsWpack[h * 8 + 4];
                wm[e] = ldsWemit[h * 16 + li];
            }
            unsigned a0, a1, a2, a3;
            asm("v_cvt_pk_bf16_f32 %0, %1, %2" : "=v"(a0) : "v"(wm[0]), "v"(wm[1]));
            asm("v_cvt_pk_bf16_f32 %0, %1, %2" : "=v"(a1) : "v"(wm[2]), "v"(wm[3]));
            asm("v_cvt_pk_bf16_f32 %0, %1, %2" : "=v"(a2) : "v"(wm[4]), "v"(wm[5]));
            asm("v_cvt_pk_bf16_f32 %0, %1, %2" : "=v"(a3) : "v"(wm[6]), "v"(wm[7]));
            union { short8 s8; uint4 u4; } au;
            au.u4 = make_uint4(a0, a1, a2, a3);

#pragma unroll
            for (int tt = 0; tt < 4; tt++) {
                float4 x = xs[tt];
                float hv[8];
#pragma unroll
                for (int e = 0; e < 8; e++) {
                    float h = fmaf(x.x, We[e][0],
                              fmaf(x.y, We[e][1],
                              fmaf(x.z, We[e][2],
                              fmaf(x.w, We[e][3], We[e][4]))));
                    hv[e] = fmaxf(h, 0.f);
                }
                unsigned u0, u1, u2, u3;
                asm("v_cvt_pk_bf16_f32 %0, %1, %2" : "=v"(u0) : "v"(hv[0]), "v"(hv[1]));
                asm("v_cvt_pk_bf16_f32 %0, %1, %2" : "=v"(u1) : "v"(hv[2]), "v"(hv[3]));
                asm("v_cvt_pk_bf16_f32 %0, %1, %2" : "=v"(u2) : "v"(hv[4]), "v"(hv[5]));
                asm("v_cvt_pk_bf16_f32 %0, %1, %2" : "=v"(u3) : "v"(hv[6]), "v"(hv[7]));
                union { short8 s8; uint4 u4; } bfu;
                bfu.u4 = make_uint4(u0, u1, u2, u3);
                acc[tt] = __builtin_amdgcn_mfma_f32_16x16x32_bf16(au.s8, bfu.s8, acc[tt], 0, 0, 0);
            }
        }

        // epilogue: +bemit, fused numerator (fp32 em), exp + bf16 store
        int len = lengths[b0];
        const int* lab = labels + (size_t)b0 * T_;
        float bm[4];
#pragma unroll
        for (int r = 0; r < 4; r++) {
            int c = 4 * g + r;
            bm[r] = (c < C_) ? bemit[c] : 0.f;
        }

        float nacc = 0.f;
#pragma unroll
        for (int tt = 0; tt < 4; tt++) {
            float em0 = acc[tt].x + bm[0];
            float em1 = acc[tt].y + bm[1];
            float em2 = acc[tt].z + bm[2];
            float em3 = acc[tt].w + bm[3];

            int t = tb0 + tt * 16 + li;
            int tg = lab[t]; tg = tg < 0 ? 0 : tg;
            if (g == (tg >> 2) && t < len) {
                int r = tg & 3;
                float emtg = r == 0 ? em0 : r == 1 ? em1 : r == 2 ? em2 : em3;
                float contrib;
                if (t == 0) {
                    contrib = startt[tg] + emtg;
                } else {
                    int tp = lab[t - 1]; tp = tp < 0 ? 0 : tp;
                    contrib = trans[tp * C_ + tg] + emtg;
                }
                if (t == len - 1) contrib += endt[tg];
                nacc += contrib;
            }

            if (g < 3) {
                float e0 = __expf(em0), e1 = __expf(em1);
                float e2 = __expf(em2), e3 = __expf(em3);
                unsigned u0, u1;
                asm("v_cvt_pk_bf16_f32 %0, %1, %2" : "=v"(u0) : "v"(e0), "v"(e1));
                asm("v_cvt_pk_bf16_f32 %0, %1, %2" : "=v"(u1) : "v"(e2), "v"(e3));
                *(uint2*)(expem + (grow0 + tt * 16 + li) * 16 + g * 4) = make_uint2(u0, u1);
            }
        }

#pragma unroll
        for (int off = 32; off > 0; off >>= 1) nacc += __shfl_down(nacc, off);
        if (lane == 0) red[wid8] = nacc;
        __syncthreads();
        if ((tid & 255) == 0)
            numpart[emb] = red[hb * 4] + red[hb * 4 + 1] + red[hb * 4 + 2] + red[hb * 4 + 3];
    }

    grid.sync();

    // ============================ phase 1 ==================================
    // chunk transfer matrices, probability domain, per-row rescale
    if (wid8 < 4) {
        int ciw = lane / C_;            // 0..5; use 0..3 (4 chunks/wave)
        int i = lane - ciw * C_;
        if (ciw < 4) {
            int cid = (bk << 4) + (wid8 << 2) + ciw;   // 0..4095, exact cover
            int b = cid >> 8;
            int k = cid & (KCH - 1);
            int t0 = 1 + k * LCH;
            int len = lengths[b];
            float* o = G0 + (size_t)cid * 132 + i * 12;

            if (t0 >= len) {             // fully inactive -> identity
#pragma unroll
                for (int j = 0; j < C_; j++) o[j] = (j == i) ? 1.f : 0.f;
                o[11] = 0.f;
            } else {
                float eT[121];
#pragma unroll
                for (int z = 0; z < 121; z++) eT[z] = __expf(trans[z]);
#pragma unroll
                for (int z = 0; z < 121; z++) asm volatile("" : "+v"(eT[z]));  // pin

                float gr[C_];
#pragma unroll
                for (int j = 0; j < C_; j++) gr[j] = (j == i) ? 1.f : 0.f;
                float ls = 0.f;

                const unsigned short* emb2 = expem + (size_t)b * T_ * 16;
                bool full = (t0 + LCH <= len);

                if (full) {
                    uint4 ca; uint2 cb;
                    loadRow(emb2 + (size_t)t0 * 16, ca, cb);
#pragma unroll 1
                    for (int su = 0; su < LCH / 4; su++) {
#pragma unroll
                        for (int ss = 0; ss < 4; ss++) {
                            int t = t0 + su * 4 + ss;
                            int tn = t + 1; tn = (tn < T_) ? tn : (T_ - 1);
                            uint4 na; uint2 nb;
                            loadRow(emb2 + (size_t)tn * 16, na, nb);   // prefetch
                            float emv[C_];
                            unpackRow(ca, cb, emv);
                            float nxt[C_];
#pragma unroll
                            for (int j = 0; j < C_; j++) nxt[j] = gr[0] * eT[j];
#pragma unroll
                            for (int kk = 1; kk < C_; kk++)
#pragma unroll
                                for (int j = 0; j < C_; j++)
                                    nxt[j] = fmaf(gr[kk], eT[kk * C_ + j], nxt[j]);
#pragma unroll
                            for (int j = 0; j < C_; j++) gr[j] = nxt[j] * emv[j];
                            ca = na; cb = nb;
                        }
                        float s = 0.f;
#pragma unroll
                        for (int j = 0; j < C_; j++) s += gr[j];
                        float r = 1.f / s;
#pragma unroll
                        for (int j = 0; j < C_; j++) gr[j] *= r;
                        ls += __logf(s);
                    }
                } else {                  // boundary chunk (rare)
#pragma unroll 1
                    for (int su = 0; su < LCH / 4; su++) {
#pragma unroll
                        for (int ss = 0; ss < 4; ss++) {
                            int t = t0 + su * 4 + ss;
                            int tc = (t < T_) ? t : (T_ - 1);
                            uint4 ca; uint2 cb;
                            loadRow(emb2 + (size_t)tc * 16, ca, cb);
                            float emv[C_];
                            unpackRow(ca, cb, emv);
                            float nxt[C_];
#pragma unroll
                            for (int j = 0; j < C_; j++) nxt[j] = gr[0] * eT[j];
#pragma unroll
                            for (int kk = 1; kk < C_; kk++)
#pragma unroll
                                for (int j = 0; j < C_; j++)
                                    nxt[j] = fmaf(gr[kk], eT[kk * C_ + j], nxt[j]);
                            bool act = (t < len);
#pragma unroll
                            for (int j = 0; j < C_; j++) gr[j] = act ? nxt[j] * emv[j] : gr[j];
                        }
                        float s = 0.f;
#pragma unroll
                        for (int j = 0; j < C_; j++) s += gr[j];
                        float r = 1.f / s;
#pragma unroll
                        for (int j = 0; j < C_; j++) gr[j] *= r;
                        ls += __logf(s);
                    }
                }

#pragma unroll
                for (int j = 0; j < C_; j++) o[j] = gr[j];
                o[11] = ls;
            }
        }
    }

    grid.sync();

    // ============================ phase 2 ==================================
    // per-batch tree combine entirely in LDS (blocks 0..15)
    if (bk < B_) {
        int b = bk;
        const float4* src = (const float4*)(G0 + (size_t)b * KCH * 132);
        float4* dst = (float4*)ldsf;
#pragma unroll 2
        for (int idx = tid; idx < KCH * 132 / 4; idx += 512) dst[idx] = src[idx];
        __syncthreads();

        for (int stride = 1; stride < KCH; stride <<= 1) {
            int npair = KCH / (2 * stride);
            for (int task = tid; task < npair * C_; task += 512) {
                int p = task / C_, i = task - p * C_;
                float* A  = ldsf + (size_t)(2 * stride * p) * 132;
                float* Bm = ldsf + (size_t)(2 * stride * p + stride) * 132;
                float a[C_];
#pragma unroll
                for (int kk = 0; kk < C_; kk++) a[kk] = A[i * 12 + kk];
                float als = A[i * 12 + 11];
                float m = Bm[11];
#pragma unroll
                for (int kk = 1; kk < C_; kk++) m = fmaxf(m, Bm[kk * 12 + 11]);
                float wv[C_];
#pragma unroll
                for (int kk = 0; kk < C_; kk++)
                    wv[kk] = a[kk] * __expf(Bm[kk * 12 + 11] - m);
                float outv[C_];
#pragma unroll
                for (int j = 0; j < C_; j++) outv[j] = wv[0] * Bm[j];
#pragma unroll
                for (int kk = 1; kk < C_; kk++)
#pragma unroll
                    for (int j = 0; j < C_; j++)
                        outv[j] = fmaf(wv[kk], Bm[kk * 12 + j], outv[j]);
                float s = 0.f;
#pragma unroll
                for (int j = 0; j < C_; j++) s += outv[j];
                float rr = 1.f / s;
#pragma unroll
                for (int j = 0; j < C_; j++) A[i * 12 + j] = outv[j] * rr;
                A[i * 12 + 11] = als + m + __logf(s);
            }
            __syncthreads();
        }

        if (tid == 0) {
            const float* Cm = ldsf;
            const unsigned short* em0 = expem + (size_t)b * T_ * 16;
            float av[C_];
            float mm = -1e30f;
#pragma unroll
            for (int i2 = 0; i2 < C_; i2++) {
                float e0 = __uint_as_float((unsigned)em0[i2] << 16);
                av[i2] = startt[i2] + __logf(e0) + Cm[i2 * 12 + 11];
                mm = fmaxf(mm, av[i2]);
            }
            float S[C_];
#pragma unroll
            for (int j = 0; j < C_; j++) S[j] = 0.f;
#pragma unroll
            for (int i2 = 0; i2 < C_; i2++) {
                float e = __expf(av[i2] - mm);
#pragma unroll
                for (int j = 0; j < C_; j++) S[j] = fmaf(e, Cm[i2 * 12 + j], S[j]);
            }
            float tot = 0.f;
#pragma unroll
            for (int j = 0; j < C_; j++) tot += S[j] * __expf(endt[j]);
            dens[b] = __logf(tot) + mm;
        }
    }

    grid.sync();

    // ============================ phase 3 ==================================
    if (bk == 0) {
        float v = numpart[tid];
        if (tid < B_) v -= dens[tid];
#pragma unroll
        for (int off = 32; off > 0; off >>= 1) v += __shfl_down(v, off);
        if (lane == 0) red[wid8] = v;
        __syncthreads();
        if (tid == 0) {
            float s = 0.f;
#pragma unroll
            for (int q = 0; q < 8; q++) s += red[q];
            out[0] = -s / (float)B_;
        }
    }
}

extern "C" void kernel_launch(void* const* d_in, const int* in_sizes, int n_in,
                              void* d_out, int out_size, void* d_ws, size_t ws_size,
                              hipStream_t stream) {
    const float* seq    = (const float*)d_in[0];
    const float* Wenc   = (const float*)d_in[1];
    const float* benc   = (const float*)d_in[2];
    const float* Wemit  = (const float*)d_in[3];
    const float* bemit  = (const float*)d_in[4];
    const float* startt = (const float*)d_in[5];
    const float* trans  = (const float*)d_in[6];
    const float* endt   = (const float*)d_in[7];
    const int*   lengths= (const int*)d_in[8];
    const int*   labels = (const int*)d_in[9];

    char* w = (char*)d_ws;
    unsigned short* expem  = (unsigned short*)w;            // B*T*16 bf16 = 4,194,304 B
    float*          G0     = (float*)(w + 4194304);         // NC*132 f32  = 2,162,688 B
    float*          numpart= (float*)(w + 6356992);         // 512 f32
    float*          dens   = (float*)(w + 6359040);         // 16 f32
    float*          outp   = (float*)d_out;

    void* args[] = {
        (void*)&seq, (void*)&Wenc, (void*)&benc, (void*)&Wemit, (void*)&bemit,
        (void*)&startt, (void*)&trans, (void*)&endt, (void*)&lengths, (void*)&labels,
        (void*)&expem, (void*)&G0, (void*)&numpart, (void*)&dens, (void*)&outp
    };
    hipLaunchCooperativeKernel((void*)k_all, dim3(256), dim3(512), args, 0, stream);
}

// Round 7
// 61.278 us; speedup vs baseline: 2.3008x; 2.3008x over previous
//
#include <hip/hip_runtime.h>
#include <hip/hip_bf16.h>

#define B_   16
#define T_   8192
#define H_   256
#define C_   11
#define KCH  256            // chunks per batch
#define LCH  32             // steps per chunk (T_/KCH)
#define NC   (B_*KCH)       // total chunks

typedef __attribute__((ext_vector_type(8))) short short8;
typedef __attribute__((ext_vector_type(4))) float f32x4;

// ---------------------------------------------------------------------------
// K1: MFMA encoder + emissions + fused numerator. Weights staged per block in
// LDS (r6 phase-0 structure, validated); fragments rebuilt per kb in-loop.
// Wave = 4 tiles x 16 rows; C/D layout col=lane&15, row=4*(lane>>4)+reg.
// Also zeroes k_comb's completion counter (stream-ordered before k_comb).
// ---------------------------------------------------------------------------
__global__ __launch_bounds__(256) void k_em(
    const float* __restrict__ seq, const float* __restrict__ Wenc,
    const float* __restrict__ benc, const float* __restrict__ Wemit,
    const float* __restrict__ bemit, const float* __restrict__ trans,
    const float* __restrict__ startt, const float* __restrict__ endt,
    const int* __restrict__ lengths, const int* __restrict__ labels,
    unsigned short* __restrict__ expem, float* __restrict__ numpart,
    unsigned* __restrict__ counter)
{
    __shared__ float ldsWpack[2048];   // [256][8]: w0..w3, benc, pad
    __shared__ float ldsWemit[4096];   // [256][16]: Wemit padded
    __shared__ float red[4];
    int tid = threadIdx.x;
    if (blockIdx.x == 0 && tid == 0) counter[0] = 0;   // reset for k_comb

    for (int idx = tid; idx < 2048; idx += 256) {
        int h = idx >> 3, s = idx & 7;
        float v = 0.f;
        if (s < 4) v = Wenc[s * H_ + h];
        else if (s == 4) v = benc[h];
        ldsWpack[idx] = v;
    }
    for (int idx = tid; idx < 4096; idx += 256) {
        int h = idx >> 4, c = idx & 15;
        ldsWemit[idx] = (c < C_) ? Wemit[h * C_ + c] : 0.f;
    }
    __syncthreads();

    int wid = tid >> 6, lane = tid & 63;
    int g = lane >> 4, li = lane & 15;
    int b0 = blockIdx.x >> 5;                     // 32 blocks per batch
    int tb0 = (blockIdx.x & 31) * 256 + wid * 64; // wave covers 64 rows
    size_t grow0 = (size_t)b0 * T_ + tb0;

    float4 xs[4];
#pragma unroll
    for (int tt = 0; tt < 4; tt++)
        xs[tt] = *(const float4*)(seq + (grow0 + tt * 16 + li) * 4);

    f32x4 acc[4];
#pragma unroll
    for (int tt = 0; tt < 4; tt++) acc[tt] = (f32x4){0.f, 0.f, 0.f, 0.f};

#pragma unroll 1
    for (int kb = 0; kb < 8; kb++) {
        float We[8][5], wm[8];
#pragma unroll
        for (int e = 0; e < 8; e++) {
            int h = 32 * kb + 4 * g + (e & 3) + 16 * (e >> 2);
            float4 w4 = *(const float4*)&ldsWpack[h * 8];
            We[e][0] = w4.x; We[e][1] = w4.y; We[e][2] = w4.z; We[e][3] = w4.w;
            We[e][4] = ldsWpack[h * 8 + 4];
            wm[e] = ldsWemit[h * 16 + li];
        }
        unsigned a0, a1, a2, a3;
        asm("v_cvt_pk_bf16_f32 %0, %1, %2" : "=v"(a0) : "v"(wm[0]), "v"(wm[1]));
        asm("v_cvt_pk_bf16_f32 %0, %1, %2" : "=v"(a1) : "v"(wm[2]), "v"(wm[3]));
        asm("v_cvt_pk_bf16_f32 %0, %1, %2" : "=v"(a2) : "v"(wm[4]), "v"(wm[5]));
        asm("v_cvt_pk_bf16_f32 %0, %1, %2" : "=v"(a3) : "v"(wm[6]), "v"(wm[7]));
        union { short8 s8; uint4 u4; } au;
        au.u4 = make_uint4(a0, a1, a2, a3);

#pragma unroll
        for (int tt = 0; tt < 4; tt++) {
            float4 x = xs[tt];
            float hv[8];
#pragma unroll
            for (int e = 0; e < 8; e++) {
                float h = fmaf(x.x, We[e][0],
                          fmaf(x.y, We[e][1],
                          fmaf(x.z, We[e][2],
                          fmaf(x.w, We[e][3], We[e][4]))));
                hv[e] = fmaxf(h, 0.f);
            }
            unsigned u0, u1, u2, u3;
            asm("v_cvt_pk_bf16_f32 %0, %1, %2" : "=v"(u0) : "v"(hv[0]), "v"(hv[1]));
            asm("v_cvt_pk_bf16_f32 %0, %1, %2" : "=v"(u1) : "v"(hv[2]), "v"(hv[3]));
            asm("v_cvt_pk_bf16_f32 %0, %1, %2" : "=v"(u2) : "v"(hv[4]), "v"(hv[5]));
            asm("v_cvt_pk_bf16_f32 %0, %1, %2" : "=v"(u3) : "v"(hv[6]), "v"(hv[7]));
            union { short8 s8; uint4 u4; } bfu;
            bfu.u4 = make_uint4(u0, u1, u2, u3);
            acc[tt] = __builtin_amdgcn_mfma_f32_16x16x32_bf16(au.s8, bfu.s8, acc[tt], 0, 0, 0);
        }
    }

    // epilogue: +bemit, fused numerator (fp32 em), exp + bf16 store
    int len = lengths[b0];
    const int* lab = labels + (size_t)b0 * T_;
    float bm[4];
#pragma unroll
    for (int r = 0; r < 4; r++) {
        int c = 4 * g + r;
        bm[r] = (c < C_) ? bemit[c] : 0.f;
    }

    float nacc = 0.f;
#pragma unroll
    for (int tt = 0; tt < 4; tt++) {
        float em0 = acc[tt].x + bm[0];
        float em1 = acc[tt].y + bm[1];
        float em2 = acc[tt].z + bm[2];
        float em3 = acc[tt].w + bm[3];

        int t = tb0 + tt * 16 + li;
        int tg = lab[t]; tg = tg < 0 ? 0 : tg;
        if (g == (tg >> 2) && t < len) {
            int r = tg & 3;
            float emtg = r == 0 ? em0 : r == 1 ? em1 : r == 2 ? em2 : em3;
            float contrib;
            if (t == 0) {
                contrib = startt[tg] + emtg;
            } else {
                int tp = lab[t - 1]; tp = tp < 0 ? 0 : tp;
                contrib = trans[tp * C_ + tg] + emtg;
            }
            if (t == len - 1) contrib += endt[tg];
            nacc += contrib;
        }

        if (g < 3) {
            float e0 = __expf(em0), e1 = __expf(em1);
            float e2 = __expf(em2), e3 = __expf(em3);
            unsigned u0, u1;
            asm("v_cvt_pk_bf16_f32 %0, %1, %2" : "=v"(u0) : "v"(e0), "v"(e1));
            asm("v_cvt_pk_bf16_f32 %0, %1, %2" : "=v"(u1) : "v"(e2), "v"(e3));
            *(uint2*)(expem + (grow0 + tt * 16 + li) * 16 + g * 4) = make_uint2(u0, u1);
        }
    }

#pragma unroll
    for (int off = 32; off > 0; off >>= 1) nacc += __shfl_down(nacc, off);
    if (lane == 0) red[wid] = nacc;
    __syncthreads();
    if (tid == 0) numpart[blockIdx.x] = red[0] + red[1] + red[2] + red[3];
}

// ---------------------------------------------------------------------------
// bf16 emission row load/unpack helpers
// ---------------------------------------------------------------------------
__device__ __forceinline__ void loadRow(const unsigned short* __restrict__ p,
                                        uint4& qa, uint2& qb) {
    qa = *(const uint4*)p;
    qb = *(const uint2*)(p + 8);
}
__device__ __forceinline__ void unpackRow(uint4 qa, uint2 qb, float* emv) {
    emv[0]  = __uint_as_float(qa.x << 16);
    emv[1]  = __uint_as_float(qa.x & 0xffff0000u);
    emv[2]  = __uint_as_float(qa.y << 16);
    emv[3]  = __uint_as_float(qa.y & 0xffff0000u);
    emv[4]  = __uint_as_float(qa.z << 16);
    emv[5]  = __uint_as_float(qa.z & 0xffff0000u);
    emv[6]  = __uint_as_float(qa.w << 16);
    emv[7]  = __uint_as_float(qa.w & 0xffff0000u);
    emv[8]  = __uint_as_float(qb.x << 16);
    emv[9]  = __uint_as_float(qb.x & 0xffff0000u);
    emv[10] = __uint_as_float(qb.y << 16);
}

// ---------------------------------------------------------------------------
// K2: per-chunk transfer matrices, probability domain, per-row rescale.
// 1 wave/block, __launch_bounds__(64,1) -> up to 256 VGPR so eT[121] stays
// register-resident; asm "+v" pins prevent rematerialization (r4/r6 failure
// mode: VGPR=36/128 -> spill/SMEM-latency-bound).
// ---------------------------------------------------------------------------
__global__ __launch_bounds__(64, 1) void k_chunks(
    const float* __restrict__ trans, const int* __restrict__ lengths,
    const unsigned short* __restrict__ expem, float* __restrict__ G)
{
    int lane = threadIdx.x;
    int ciw = lane / C_;            // 5 chunks per wave (55/64 lanes)
    int i = lane - ciw * C_;
    int cid = blockIdx.x * 5 + ciw;
    if (ciw >= 5 || cid >= NC) return;

    int b = cid >> 8;
    int k = cid & (KCH - 1);
    int t0 = 1 + k * LCH;
    int len = lengths[b];
    float* o = G + (size_t)cid * 132 + i * 12;

    if (t0 >= len) {                 // fully inactive -> identity
#pragma unroll
        for (int j = 0; j < C_; j++) o[j] = (j == i) ? 1.f : 0.f;
        o[11] = 0.f;
        return;
    }

    float eT[121];
#pragma unroll
    for (int z = 0; z < 121; z++) eT[z] = __expf(trans[z]);
#pragma unroll
    for (int z = 0; z < 121; z++) asm volatile("" : "+v"(eT[z]));  // pin in VGPR

    float g[C_];
#pragma unroll
    for (int j = 0; j < C_; j++) g[j] = (j == i) ? 1.f : 0.f;
    float ls = 0.f;

    const unsigned short* emb = expem + (size_t)b * T_ * 16;
    bool full = (t0 + LCH <= len);

    if (full) {
        uint4 ca; uint2 cb;
        loadRow(emb + (size_t)t0 * 16, ca, cb);
#pragma unroll 1
        for (int su = 0; su < LCH / 4; su++) {
#pragma unroll
            for (int ss = 0; ss < 4; ss++) {
                int t = t0 + su * 4 + ss;
                int tn = t + 1; tn = (tn < T_) ? tn : (T_ - 1);
                uint4 na; uint2 nb;
                loadRow(emb + (size_t)tn * 16, na, nb);   // prefetch next
                float emv[C_];
                unpackRow(ca, cb, emv);
                float nxt[C_];
#pragma unroll
                for (int j = 0; j < C_; j++) nxt[j] = g[0] * eT[j];
#pragma unroll
                for (int kk = 1; kk < C_; kk++)
#pragma unroll
                    for (int j = 0; j < C_; j++)
                        nxt[j] = fmaf(g[kk], eT[kk * C_ + j], nxt[j]);
#pragma unroll
                for (int j = 0; j < C_; j++) g[j] = nxt[j] * emv[j];
                ca = na; cb = nb;
            }
            float s = 0.f;
#pragma unroll
            for (int j = 0; j < C_; j++) s += g[j];
            float r = 1.f / s;
#pragma unroll
            for (int j = 0; j < C_; j++) g[j] *= r;
            ls += __logf(s);
        }
    } else {                          // boundary chunk (rare)
#pragma unroll 1
        for (int su = 0; su < LCH / 4; su++) {
#pragma unroll
            for (int ss = 0; ss < 4; ss++) {
                int t = t0 + su * 4 + ss;
                int tc = (t < T_) ? t : (T_ - 1);
                uint4 ca; uint2 cb;
                loadRow(emb + (size_t)tc * 16, ca, cb);
                float emv[C_];
                unpackRow(ca, cb, emv);
                float nxt[C_];
#pragma unroll
                for (int j = 0; j < C_; j++) nxt[j] = g[0] * eT[j];
#pragma unroll
                for (int kk = 1; kk < C_; kk++)
#pragma unroll
                    for (int j = 0; j < C_; j++)
                        nxt[j] = fmaf(g[kk], eT[kk * C_ + j], nxt[j]);
                bool act = (t < len);
#pragma unroll
                for (int j = 0; j < C_; j++) g[j] = act ? nxt[j] * emv[j] : g[j];
            }
            float s = 0.f;
#pragma unroll
            for (int j = 0; j < C_; j++) s += g[j];
            float r = 1.f / s;
#pragma unroll
            for (int j = 0; j < C_; j++) g[j] *= r;
            ls += __logf(s);
        }
    }

#pragma unroll
    for (int j = 0; j < C_; j++) o[j] = g[j];
    o[11] = ls;
}

// ---------------------------------------------------------------------------
// K3: per-batch LDS tree combine + den + FUSED final reduction.
// Each block b computes loss_b = num_b - den_b, publishes device-scope;
// last block (atomic counter, zeroed by k_em) sums in fixed order -> out.
// ---------------------------------------------------------------------------
__global__ __launch_bounds__(512, 1) void k_comb(
    const float* __restrict__ startt, const float* __restrict__ endt,
    const unsigned short* __restrict__ expem, const float* __restrict__ G0,
    const float* __restrict__ numpart, float* __restrict__ dens,
    unsigned* __restrict__ counter, float* __restrict__ out)
{
    __shared__ float M[KCH * 132];     // 135168 bytes
    int b = blockIdx.x, tid = threadIdx.x;

    // numerator for this batch (32 k_em block slots), result on tid 0
    float numb = 0.f;
    if (tid < 64) {
        float v = (tid < 32) ? numpart[b * 32 + tid] : 0.f;
#pragma unroll
        for (int off = 32; off > 0; off >>= 1) v += __shfl_down(v, off);
        numb = v;                       // valid on tid 0
    }

    const float4* src = (const float4*)(G0 + (size_t)b * KCH * 132);
    float4* dst = (float4*)M;
#pragma unroll 2
    for (int idx = tid; idx < KCH * 132 / 4; idx += 512) dst[idx] = src[idx];
    __syncthreads();

    for (int stride = 1; stride < KCH; stride <<= 1) {
        int npair = KCH / (2 * stride);
        for (int task = tid; task < npair * C_; task += 512) {
            int p = task / C_, i = task - p * C_;
            float* A  = M + (size_t)(2 * stride * p) * 132;
            float* Bm = M + (size_t)(2 * stride * p + stride) * 132;
            float a[C_];
#pragma unroll
            for (int kk = 0; kk < C_; kk++) a[kk] = A[i * 12 + kk];
            float als = A[i * 12 + 11];
            float m = Bm[11];
#pragma unroll
            for (int kk = 1; kk < C_; kk++) m = fmaxf(m, Bm[kk * 12 + 11]);
            float wv[C_];
#pragma unroll
            for (int kk = 0; kk < C_; kk++)
                wv[kk] = a[kk] * __expf(Bm[kk * 12 + 11] - m);
            float outv[C_];
#pragma unroll
            for (int j = 0; j < C_; j++) outv[j] = wv[0] * Bm[j];
#pragma unroll
            for (int kk = 1; kk < C_; kk++)
#pragma unroll
                for (int j = 0; j < C_; j++)
                    outv[j] = fmaf(wv[kk], Bm[kk * 12 + j], outv[j]);
            float s = 0.f;
#pragma unroll
            for (int j = 0; j < C_; j++) s += outv[j];
            float rr = 1.f / s;
#pragma unroll
            for (int j = 0; j < C_; j++) A[i * 12 + j] = outv[j] * rr;
            A[i * 12 + 11] = als + m + __logf(s);
        }
        __syncthreads();
    }

    if (tid == 0) {
        const float* Cm = M;
        const unsigned short* em0 = expem + (size_t)b * T_ * 16;
        float av[C_];
        float mm = -1e30f;
#pragma unroll
        for (int i2 = 0; i2 < C_; i2++) {
            float e0 = __uint_as_float((unsigned)em0[i2] << 16);
            av[i2] = startt[i2] + __logf(e0) + Cm[i2 * 12 + 11];
            mm = fmaxf(mm, av[i2]);
        }
        float S[C_];
#pragma unroll
        for (int j = 0; j < C_; j++) S[j] = 0.f;
#pragma unroll
        for (int i2 = 0; i2 < C_; i2++) {
            float e = __expf(av[i2] - mm);
#pragma unroll
            for (int j = 0; j < C_; j++) S[j] = fmaf(e, Cm[i2 * 12 + j], S[j]);
        }
        float tot = 0.f;
#pragma unroll
        for (int j = 0; j < C_; j++) tot += S[j] * __expf(endt[j]);
        float den = __logf(tot) + mm;

        float loss = numb - den;
        __hip_atomic_store(&dens[b], loss, __ATOMIC_RELEASE, __HIP_MEMORY_SCOPE_AGENT);
        unsigned old = __hip_atomic_fetch_add(counter, 1u, __ATOMIC_ACQ_REL,
                                              __HIP_MEMORY_SCOPE_AGENT);
        if (old == B_ - 1) {            // last block: fixed-order sum (deterministic)
            float s = 0.f;
#pragma unroll
            for (int j = 0; j < B_; j++)
                s += __hip_atomic_load(&dens[j], __ATOMIC_ACQUIRE,
                                       __HIP_MEMORY_SCOPE_AGENT);
            out[0] = -s / (float)B_;
        }
    }
}

extern "C" void kernel_launch(void* const* d_in, const int* in_sizes, int n_in,
                              void* d_out, int out_size, void* d_ws, size_t ws_size,
                              hipStream_t stream) {
    const float* seq    = (const float*)d_in[0];
    const float* Wenc   = (const float*)d_in[1];
    const float* benc   = (const float*)d_in[2];
    const float* Wemit  = (const float*)d_in[3];
    const float* bemit  = (const float*)d_in[4];
    const float* startt = (const float*)d_in[5];
    const float* trans  = (const float*)d_in[6];
    const float* endt   = (const float*)d_in[7];
    const int*   lengths= (const int*)d_in[8];
    const int*   labels = (const int*)d_in[9];

    char* w = (char*)d_ws;
    unsigned short* expem  = (unsigned short*)w;            // B*T*16 bf16 = 4,194,304 B
    float*          G0     = (float*)(w + 4194304);         // NC*132 f32  = 2,162,688 B
    float*          numpart= (float*)(w + 6356992);         // 512 f32
    float*          dens   = (float*)(w + 6359040);         // 16 f32
    unsigned*       counter= (unsigned*)(w + 6359104);      // 1 u32
    float*          out    = (float*)d_out;

    k_em<<<512, 256, 0, stream>>>(seq, Wenc, benc, Wemit, bemit, trans,
                                  startt, endt, lengths, labels,
                                  expem, numpart, counter);
    k_chunks<<<(NC + 4) / 5, 64, 0, stream>>>(trans, lengths, expem, G0);
    k_comb<<<B_, 512, 0, stream>>>(startt, endt, expem, G0, numpart,
                                   dens, counter, out);
}